// Round 2
// baseline (444.633 us; speedup 1.0000x reference)
//
#include <hip/hip_runtime.h>
#include <stdint.h>
#include <stddef.h>

typedef __attribute__((ext_vector_type(8))) short bf16x8;
typedef __attribute__((ext_vector_type(4))) float f32x4;

#define DMODEL 1536
#define TSEQ   2048
#define HDIM   128
#define NBR    3
#define NHB    4      // heads per branch
#define MROWS  4096   // B*T

__device__ __forceinline__ float bf2f(unsigned short u) {
  union { unsigned int i; float f; } v; v.i = ((unsigned int)u) << 16; return v.f;
}
__device__ __forceinline__ unsigned short f2bf(float f) {
  union { float f; unsigned int i; } v; v.f = f;
  unsigned int r = v.i + 0x7fffu + ((v.i >> 16) & 1u);
  return (unsigned short)(r >> 16);
}
__device__ __forceinline__ void gload_lds16(const void* g, void* l) {
  __builtin_amdgcn_global_load_lds((__attribute__((address_space(1))) void*)g,
                                   (__attribute__((address_space(3))) void*)l,
                                   16, 0, 0);
}

// ---------------------------------------------------------------------------
// f32 -> bf16 conversion kernels (pre-pass)
// ---------------------------------------------------------------------------
__global__ __launch_bounds__(256) void k_cvt(const float* __restrict__ src,
                                             unsigned short* __restrict__ dst,
                                             int n4) {
  int i = blockIdx.x * 256 + threadIdx.x;
  if (i >= n4) return;
  float4 v = ((const float4*)src)[i];
  ushort4 o;
  o.x = f2bf(v.x); o.y = f2bf(v.y); o.z = f2bf(v.z); o.w = f2bf(v.w);
  ((ushort4*)dst)[i] = o;
}

struct W9 { const float* w[9]; };

__global__ __launch_bounds__(256) void k_cvt9(W9 ws, unsigned short* __restrict__ dst,
                                              int n4) {
  int seg = blockIdx.y;
  const float* __restrict__ src = ws.w[seg];
  unsigned short* __restrict__ d = dst + (size_t)seg * (size_t)n4 * 4;
  int i = blockIdx.x * 256 + threadIdx.x;
  if (i >= n4) return;
  float4 v = ((const float4*)src)[i];
  ushort4 o;
  o.x = f2bf(v.x); o.y = f2bf(v.y); o.z = f2bf(v.z); o.w = f2bf(v.w);
  ((ushort4*)d)[i] = o;
}

// ---------------------------------------------------------------------------
// 128x128 tile GEMM core: C = A[M,K] * B[N,K]^T, bf16 in, f32 acc.
// 256 threads = 4 waves (2x2), each wave 64x64 via 4x4 frags of 16x16x32.
// ---------------------------------------------------------------------------
__device__ __forceinline__ void gemm_core_128(
    const unsigned short* __restrict__ A, const unsigned short* __restrict__ Bw,
    int K, int m0, int n0,
    unsigned short* As, unsigned short* Bs, f32x4 acc[4][4])
{
  const int t  = threadIdx.x;
  const int ln = t & 63, w = t >> 6;
  const int wr = w >> 1, wc = w & 1;
  const int g  = ln >> 4, li = ln & 15;

  for (int k0 = 0; k0 < K; k0 += 64) {
    // stage A-tile [128][64] and B-tile [128][64] (linear, lds-direct)
#pragma unroll
    for (int i = 0; i < 4; ++i) {
      int chunk = i * 256 + t;           // 1024 chunks of 16B each
      int row = chunk >> 3, c16 = chunk & 7;
      gload_lds16(A  + (size_t)(m0 + row) * K + k0 + c16 * 8, As + chunk * 8);
      gload_lds16(Bw + (size_t)(n0 + row) * K + k0 + c16 * 8, Bs + chunk * 8);
    }
    __syncthreads();
#pragma unroll
    for (int s = 0; s < 2; ++s) {
      bf16x8 af[4], bfr[4];
#pragma unroll
      for (int mi = 0; mi < 4; ++mi)
        af[mi] = *(const bf16x8*)(As + (wr*64 + mi*16 + li) * 64 + s*32 + g*8);
#pragma unroll
      for (int ni = 0; ni < 4; ++ni)
        bfr[ni] = *(const bf16x8*)(Bs + (wc*64 + ni*16 + li) * 64 + s*32 + g*8);
#pragma unroll
      for (int mi = 0; mi < 4; ++mi)
#pragma unroll
        for (int ni = 0; ni < 4; ++ni)
          acc[mi][ni] = __builtin_amdgcn_mfma_f32_16x16x32_bf16(
              af[mi], bfr[ni], acc[mi][ni], 0, 0, 0);
    }
    __syncthreads();
  }
}

// ---------------------------------------------------------------------------
// QKV projections: mat = 0..8 (wq_f,wk_f,wv_f,wq_b,...,wv_d)
// scatter into slabs [br][b][h][t][128] (bf16)
// ---------------------------------------------------------------------------
__global__ __launch_bounds__(256) void k_gemm_qkv(
    const unsigned short* __restrict__ X, const unsigned short* __restrict__ Wall,
    unsigned short* __restrict__ Qs, unsigned short* __restrict__ Ksl,
    unsigned short* __restrict__ Vs)
{
  __shared__ __align__(16) unsigned short As[128 * 64];
  __shared__ __align__(16) unsigned short Bs[128 * 64];

  const int mat = blockIdx.z;
  const unsigned short* W = Wall + (size_t)mat * 512 * DMODEL;
  const int m0 = blockIdx.x * 128, n0 = blockIdx.y * 128;

  f32x4 zero4 = {0.f, 0.f, 0.f, 0.f};
  f32x4 acc[4][4];
#pragma unroll
  for (int i = 0; i < 4; ++i)
#pragma unroll
    for (int j = 0; j < 4; ++j) acc[i][j] = zero4;

  gemm_core_128(X, W, DMODEL, m0, n0, As, Bs, acc);

  const int t = threadIdx.x, ln = t & 63, w = t >> 6;
  const int wr = w >> 1, wc = w & 1, g = ln >> 4, li = ln & 15;
  const int br = mat / 3, qkv = mat % 3;
  unsigned short* dst = (qkv == 0) ? Qs : (qkv == 1) ? Ksl : Vs;

#pragma unroll
  for (int mi = 0; mi < 4; ++mi)
#pragma unroll
    for (int ni = 0; ni < 4; ++ni)
#pragma unroll
      for (int r = 0; r < 4; ++r) {
        int row = m0 + wr*64 + mi*16 + g*4 + r;   // 0..4095 = b*2048+t
        int col = n0 + wc*64 + ni*16 + li;        // 0..511  = h*128+d
        int b = row >> 11, tt = row & 2047;
        int h = col >> 7,  d  = col & 127;
        size_t off = ((size_t)((br*2 + b)*4 + h) * TSEQ + tt) * HDIM + d;
        dst[off] = f2bf(acc[mi][ni][r]);
      }
}

// ---------------------------------------------------------------------------
// Output projection: C[4096,1536] = AO @ wo^T -> d_out (f32)
// ---------------------------------------------------------------------------
__global__ __launch_bounds__(256) void k_gemm_out(
    const unsigned short* __restrict__ AO, const unsigned short* __restrict__ WO,
    float* __restrict__ Cout)
{
  __shared__ __align__(16) unsigned short As[128 * 64];
  __shared__ __align__(16) unsigned short Bs[128 * 64];

  const int m0 = blockIdx.x * 128, n0 = blockIdx.y * 128;
  f32x4 zero4 = {0.f, 0.f, 0.f, 0.f};
  f32x4 acc[4][4];
#pragma unroll
  for (int i = 0; i < 4; ++i)
#pragma unroll
    for (int j = 0; j < 4; ++j) acc[i][j] = zero4;

  gemm_core_128(AO, WO, DMODEL, m0, n0, As, Bs, acc);

  const int t = threadIdx.x, ln = t & 63, w = t >> 6;
  const int wr = w >> 1, wc = w & 1, g = ln >> 4, li = ln & 15;
#pragma unroll
  for (int mi = 0; mi < 4; ++mi)
#pragma unroll
    for (int ni = 0; ni < 4; ++ni)
#pragma unroll
      for (int r = 0; r < 4; ++r) {
        int row = m0 + wr*64 + mi*16 + g*4 + r;
        int col = n0 + wc*64 + ni*16 + li;
        Cout[(size_t)row * DMODEL + col] = acc[mi][ni][r];
      }
}

// ---------------------------------------------------------------------------
// RMSNorm + RoPE in place on Q,K slabs (bf16). One wave per row.
// lane l owns pair (d=l, d=l+64); cos/sin identical for the pair.
// ---------------------------------------------------------------------------
__global__ __launch_bounds__(256) void k_rope(
    unsigned short* __restrict__ Q, unsigned short* __restrict__ K,
    const float* __restrict__ qw, const float* __restrict__ kw)
{
  const int t = threadIdx.x, ln = t & 63, w = t >> 6;
  const int rid = blockIdx.x * 4 + w;          // 0..49151
  const int tt  = rid & (TSEQ - 1);
  const size_t base = (size_t)rid * HDIM;

  // inv_freq = theta^(-ln/64) = exp2(-ln * log2(1e6)/64)
  const float ang = (float)tt * exp2f(-0.31143075464f * (float)ln);
  float s, c;
  sincosf(ang, &s, &c);

#pragma unroll
  for (int which = 0; which < 2; ++which) {
    unsigned short* P = which ? K : Q;
    const float* Wn = which ? kw : qw;
    float x1 = bf2f(P[base + ln]);
    float x2 = bf2f(P[base + 64 + ln]);
    float ss = x1 * x1 + x2 * x2;
#pragma unroll
    for (int off = 1; off < 64; off <<= 1) ss += __shfl_xor(ss, off, 64);
    float rr = rsqrtf(ss * (1.0f / 128.0f) + 1.1920928955078125e-07f);
    float y1 = x1 * rr * Wn[ln];
    float y2 = x2 * rr * Wn[64 + ln];
    P[base + ln]      = f2bf(y1 * c - y2 * s);
    P[base + 64 + ln] = f2bf(y2 * c + y1 * s);
  }
}

// ---------------------------------------------------------------------------
// Flash attention. grid = (32 qtiles, 8 = b*4+h, 3 branches), 256 thr = 4 waves.
// Wave w owns q rows [q0+16w, q0+16w+16). KV tile = 64.
// ---------------------------------------------------------------------------
#define ATT_SCALE 0.08838834764831845f

__global__ __launch_bounds__(256) void k_attn(
    const unsigned short* __restrict__ Q, const unsigned short* __restrict__ K,
    const unsigned short* __restrict__ V, unsigned short* __restrict__ AO)
{
  __shared__ __align__(16) unsigned short Ks[64 * 136];   // K tile, +8 pad
  __shared__ __align__(16) unsigned short Vt[128 * 72];   // V^T tile, +8 pad
  __shared__ __align__(16) unsigned short Ps[4 * 16 * 72];// per-wave P, +8 pad

  const int qt = blockIdx.x;
  const int bh = blockIdx.y;
  const int br = blockIdx.z;
  const int b = bh >> 2, h = bh & 3;
  const int t = threadIdx.x, ln = t & 63, w = t >> 6;
  const int g = ln >> 4, li = ln & 15;
  const size_t slab = (size_t)(br * 8 + bh) * (TSEQ * HDIM);
  const int q0 = qt * 64;

  // Q fragments: 4 k-slices of 32, lane l: row = li, d = s*32 + g*8 + j
  bf16x8 qf[4];
  {
    const unsigned short* qp = Q + slab + (size_t)(q0 + w*16 + li) * HDIM + g*8;
#pragma unroll
    for (int s = 0; s < 4; ++s) qf[s] = *(const bf16x8*)(qp + s * 32);
  }

  f32x4 zero4 = {0.f, 0.f, 0.f, 0.f};
  f32x4 acc_o[8];
#pragma unroll
  for (int fd = 0; fd < 8; ++fd) acc_o[fd] = zero4;
  float m_run[4], l_run[4];
#pragma unroll
  for (int r = 0; r < 4; ++r) { m_run[r] = -1e30f; l_run[r] = 0.f; }

  const int kt0 = (br == 1) ? qt : 0;
  const int kt1 = (br == 0) ? qt : 31;
  unsigned short* Pw = Ps + w * (16 * 72);

  for (int kt = kt0; kt <= kt1; ++kt) {
    const int k0 = kt * 64;
    __syncthreads();   // prior tile's LDS reads done

    // stage K tile [64][128] -> Ks[kr][d], row stride 136
#pragma unroll
    for (int i = 0; i < 4; ++i) {
      int c2 = i * 256 + t;                 // 1024 chunks of 8 elems
      int kr = c2 >> 4, c16 = c2 & 15;
      *(bf16x8*)(Ks + kr * 136 + c16 * 8) =
          *(const bf16x8*)(K + slab + (size_t)(k0 + kr) * HDIM + c16 * 8);
    }
    // stage V transposed: Vt[d][kr], row stride 72
#pragma unroll
    for (int i = 0; i < 4; ++i) {
      int c2 = i * 256 + t;
      int kr = c2 >> 4, d0 = (c2 & 15) * 8;
      bf16x8 vv = *(const bf16x8*)(V + slab + (size_t)(k0 + kr) * HDIM + d0);
#pragma unroll
      for (int j = 0; j < 8; ++j) Vt[(d0 + j) * 72 + kr] = (unsigned short)vv[j];
    }
    __syncthreads();

    // S = Q K^T : per wave 16q x 64k
    f32x4 sf[4];
#pragma unroll
    for (int fc = 0; fc < 4; ++fc) sf[fc] = zero4;
#pragma unroll
    for (int s = 0; s < 4; ++s) {
      bf16x8 kf[4];
#pragma unroll
      for (int fc = 0; fc < 4; ++fc)
        kf[fc] = *(const bf16x8*)(Ks + (fc*16 + li) * 136 + s*32 + g*8);
#pragma unroll
      for (int fc = 0; fc < 4; ++fc)
        sf[fc] = __builtin_amdgcn_mfma_f32_16x16x32_bf16(qf[s], kf[fc], sf[fc], 0, 0, 0);
    }

    const bool diag = (br != 2) && (kt == qt);
    float pp[4][4];
#pragma unroll
    for (int fc = 0; fc < 4; ++fc)
#pragma unroll
      for (int r = 0; r < 4; ++r) {
        float sv = sf[fc][r] * ATT_SCALE;
        if (diag) {
          int kg = k0 + fc*16 + li;
          int qg = q0 + w*16 + g*4 + r;
          bool ok = (br == 0) ? (kg <= qg) : (kg >= qg);
          sv = ok ? sv : -1e30f;
        }
        pp[fc][r] = sv;
      }

    // online softmax per row (rows owned by 16-lane groups)
#pragma unroll
    for (int r = 0; r < 4; ++r) {
      float rm = fmaxf(fmaxf(pp[0][r], pp[1][r]), fmaxf(pp[2][r], pp[3][r]));
      rm = fmaxf(rm, __shfl_xor(rm, 1, 64));
      rm = fmaxf(rm, __shfl_xor(rm, 2, 64));
      rm = fmaxf(rm, __shfl_xor(rm, 4, 64));
      rm = fmaxf(rm, __shfl_xor(rm, 8, 64));
      float mn = fmaxf(m_run[r], rm);
      float alpha = __expf(m_run[r] - mn);
      m_run[r] = mn;
      float rs = 0.f;
#pragma unroll
      for (int fc = 0; fc < 4; ++fc) {
        float p = __expf(pp[fc][r] - mn);
        pp[fc][r] = p;
        rs += p;
      }
      rs += __shfl_xor(rs, 1, 64);
      rs += __shfl_xor(rs, 2, 64);
      rs += __shfl_xor(rs, 4, 64);
      rs += __shfl_xor(rs, 8, 64);
      l_run[r] = l_run[r] * alpha + rs;
#pragma unroll
      for (int fd = 0; fd < 8; ++fd) acc_o[fd][r] *= alpha;
    }

    // P -> LDS (wave-private region), then PV
#pragma unroll
    for (int fc = 0; fc < 4; ++fc)
#pragma unroll
      for (int r = 0; r < 4; ++r)
        Pw[(g*4 + r) * 72 + fc*16 + li] = f2bf(pp[fc][r]);

    asm volatile("s_waitcnt lgkmcnt(0)" ::: "memory");
    __builtin_amdgcn_sched_barrier(0);

#pragma unroll
    for (int ks = 0; ks < 2; ++ks) {
      bf16x8 pa = *(const bf16x8*)(Pw + li * 72 + ks*32 + g*8);
#pragma unroll
      for (int fd = 0; fd < 8; ++fd) {
        bf16x8 vb = *(const bf16x8*)(Vt + (fd*16 + li) * 72 + ks*32 + g*8);
        acc_o[fd] = __builtin_amdgcn_mfma_f32_16x16x32_bf16(pa, vb, acc_o[fd], 0, 0, 0);
      }
    }
  }

  // epilogue: AO[b][t][br*512 + h*128 + d]
#pragma unroll
  for (int r = 0; r < 4; ++r) {
    float inv = 1.0f / l_run[r];
    int tt = q0 + w*16 + g*4 + r;
    size_t rowbase = ((size_t)b * TSEQ + tt) * DMODEL + br * 512 + h * HDIM;
#pragma unroll
    for (int fd = 0; fd < 8; ++fd)
      AO[rowbase + fd*16 + li] = f2bf(acc_o[fd][r] * inv);
  }
}

// ---------------------------------------------------------------------------
extern "C" void kernel_launch(void* const* d_in, const int* in_sizes, int n_in,
                              void* d_out, int out_size, void* d_ws, size_t ws_size,
                              hipStream_t stream)
{
  (void)in_sizes; (void)n_in; (void)out_size; (void)ws_size;
  const float* Xf  = (const float*)d_in[0];
  const float* WOf = (const float*)d_in[10];
  const float* qw  = (const float*)d_in[11];
  const float* kw  = (const float*)d_in[12];

  const size_t S = (size_t)NBR * 2 * NHB * TSEQ * HDIM;       // 6,291,456 elems
  unsigned short* Qs   = (unsigned short*)d_ws;                // S
  unsigned short* Ks   = Qs + S;                               // S
  unsigned short* Vs   = Ks + S;                               // S
  unsigned short* AO   = Vs + S;                               // S
  unsigned short* Xbf  = AO + S;                               // 6,291,456
  unsigned short* Wbf  = Xbf + (size_t)MROWS * DMODEL;         // 9*512*1536
  unsigned short* WObf = Wbf + (size_t)9 * 512 * DMODEL;       // 1536*1536
  float* Cout = (float*)d_out;

  dim3 blk(256);

  // f32 -> bf16 conversions
  k_cvt<<<dim3((MROWS * DMODEL) / 1024), blk, 0, stream>>>(Xf, Xbf, (MROWS * DMODEL) / 4);
  W9 w9;
  for (int i = 0; i < 9; ++i) w9.w[i] = (const float*)d_in[1 + i];
  k_cvt9<<<dim3((512 * DMODEL) / 1024, 9), blk, 0, stream>>>(w9, Wbf, (512 * DMODEL) / 4);
  k_cvt<<<dim3((DMODEL * DMODEL) / 1024), blk, 0, stream>>>(WOf, WObf, (DMODEL * DMODEL) / 4);

  k_gemm_qkv<<<dim3(32, 4, 9), blk, 0, stream>>>(Xbf, Wbf, Qs, Ks, Vs);
  k_rope<<<dim3(12288), blk, 0, stream>>>(Qs, Ks, qw, kw);
  k_attn<<<dim3(32, 8, 3), blk, 0, stream>>>(Qs, Ks, Vs, AO);
  k_gemm_out<<<dim3(32, 12), blk, 0, stream>>>(AO, WObf, Cout);
}

// Round 3
// 270.685 us; speedup vs baseline: 1.6426x; 1.6426x over previous
//
#include <hip/hip_runtime.h>
#include <stdint.h>
#include <stddef.h>

typedef __attribute__((ext_vector_type(8))) short bf16x8;
typedef __attribute__((ext_vector_type(4))) float f32x4;

#define DMODEL 1536
#define TSEQ   2048
#define HDIM   128
#define NBR    3
#define NHB    4      // heads per branch
#define MROWS  4096   // B*T

__device__ __forceinline__ float bf2f(unsigned short u) {
  union { unsigned int i; float f; } v; v.i = ((unsigned int)u) << 16; return v.f;
}
__device__ __forceinline__ unsigned short f2bf(float f) {
  union { float f; unsigned int i; } v; v.f = f;
  unsigned int r = v.i + 0x7fffu + ((v.i >> 16) & 1u);
  return (unsigned short)(r >> 16);
}
__device__ __forceinline__ void gload_lds16(const void* g, void* l) {
  __builtin_amdgcn_global_load_lds((__attribute__((address_space(1))) void*)g,
                                   (__attribute__((address_space(3))) void*)l,
                                   16, 0, 0);
}

// ---------------------------------------------------------------------------
// f32 -> bf16 conversion kernels (pre-pass)
// ---------------------------------------------------------------------------
__global__ __launch_bounds__(256) void k_cvt(const float* __restrict__ src,
                                             unsigned short* __restrict__ dst,
                                             int n4) {
  int i = blockIdx.x * 256 + threadIdx.x;
  if (i >= n4) return;
  float4 v = ((const float4*)src)[i];
  ushort4 o;
  o.x = f2bf(v.x); o.y = f2bf(v.y); o.z = f2bf(v.z); o.w = f2bf(v.w);
  ((ushort4*)dst)[i] = o;
}

struct W9 { const float* w[9]; };

__global__ __launch_bounds__(256) void k_cvt9(W9 ws, unsigned short* __restrict__ dst,
                                              int n4) {
  int seg = blockIdx.y;
  const float* __restrict__ src = ws.w[seg];
  unsigned short* __restrict__ d = dst + (size_t)seg * (size_t)n4 * 4;
  int i = blockIdx.x * 256 + threadIdx.x;
  if (i >= n4) return;
  float4 v = ((const float4*)src)[i];
  ushort4 o;
  o.x = f2bf(v.x); o.y = f2bf(v.y); o.z = f2bf(v.z); o.w = f2bf(v.w);
  ((ushort4*)d)[i] = o;
}

// ---------------------------------------------------------------------------
// 128x128 tile GEMM core: C = A[M,K] * B[N,K]^T, bf16 in, f32 acc.
// ---------------------------------------------------------------------------
__device__ __forceinline__ void gemm_core_128(
    const unsigned short* __restrict__ A, const unsigned short* __restrict__ Bw,
    int K, int m0, int n0,
    unsigned short* As, unsigned short* Bs, f32x4 acc[4][4])
{
  const int t  = threadIdx.x;
  const int ln = t & 63, w = t >> 6;
  const int wr = w >> 1, wc = w & 1;
  const int g  = ln >> 4, li = ln & 15;

  for (int k0 = 0; k0 < K; k0 += 64) {
#pragma unroll
    for (int i = 0; i < 4; ++i) {
      int chunk = i * 256 + t;           // 1024 chunks of 16B each
      int row = chunk >> 3, c16 = chunk & 7;
      gload_lds16(A  + (size_t)(m0 + row) * K + k0 + c16 * 8, As + chunk * 8);
      gload_lds16(Bw + (size_t)(n0 + row) * K + k0 + c16 * 8, Bs + chunk * 8);
    }
    __syncthreads();
#pragma unroll
    for (int s = 0; s < 2; ++s) {
      bf16x8 af[4], bfr[4];
#pragma unroll
      for (int mi = 0; mi < 4; ++mi)
        af[mi] = *(const bf16x8*)(As + (wr*64 + mi*16 + li) * 64 + s*32 + g*8);
#pragma unroll
      for (int ni = 0; ni < 4; ++ni)
        bfr[ni] = *(const bf16x8*)(Bs + (wc*64 + ni*16 + li) * 64 + s*32 + g*8);
#pragma unroll
      for (int mi = 0; mi < 4; ++mi)
#pragma unroll
        for (int ni = 0; ni < 4; ++ni)
          acc[mi][ni] = __builtin_amdgcn_mfma_f32_16x16x32_bf16(
              af[mi], bfr[ni], acc[mi][ni], 0, 0, 0);
    }
    __syncthreads();
  }
}

// ---------------------------------------------------------------------------
// QKV projections -> slabs [br][b][h][t][128] (bf16)
// ---------------------------------------------------------------------------
__global__ __launch_bounds__(256) void k_gemm_qkv(
    const unsigned short* __restrict__ X, const unsigned short* __restrict__ Wall,
    unsigned short* __restrict__ Qs, unsigned short* __restrict__ Ksl,
    unsigned short* __restrict__ Vs)
{
  __shared__ __align__(16) unsigned short As[128 * 64];
  __shared__ __align__(16) unsigned short Bs[128 * 64];

  const int mat = blockIdx.z;
  const unsigned short* W = Wall + (size_t)mat * 512 * DMODEL;
  const int m0 = blockIdx.x * 128, n0 = blockIdx.y * 128;

  f32x4 zero4 = {0.f, 0.f, 0.f, 0.f};
  f32x4 acc[4][4];
#pragma unroll
  for (int i = 0; i < 4; ++i)
#pragma unroll
    for (int j = 0; j < 4; ++j) acc[i][j] = zero4;

  gemm_core_128(X, W, DMODEL, m0, n0, As, Bs, acc);

  const int t = threadIdx.x, ln = t & 63, w = t >> 6;
  const int wr = w >> 1, wc = w & 1, g = ln >> 4, li = ln & 15;
  const int br = mat / 3, qkv = mat % 3;
  unsigned short* dst = (qkv == 0) ? Qs : (qkv == 1) ? Ksl : Vs;

#pragma unroll
  for (int mi = 0; mi < 4; ++mi)
#pragma unroll
    for (int ni = 0; ni < 4; ++ni)
#pragma unroll
      for (int r = 0; r < 4; ++r) {
        int row = m0 + wr*64 + mi*16 + g*4 + r;   // 0..4095 = b*2048+t
        int col = n0 + wc*64 + ni*16 + li;        // 0..511  = h*128+d
        int b = row >> 11, tt = row & 2047;
        int h = col >> 7,  d  = col & 127;
        size_t off = ((size_t)((br*2 + b)*4 + h) * TSEQ + tt) * HDIM + d;
        dst[off] = f2bf(acc[mi][ni][r]);
      }
}

// ---------------------------------------------------------------------------
// Output projection -> d_out (f32)
// ---------------------------------------------------------------------------
__global__ __launch_bounds__(256) void k_gemm_out(
    const unsigned short* __restrict__ AO, const unsigned short* __restrict__ WO,
    float* __restrict__ Cout)
{
  __shared__ __align__(16) unsigned short As[128 * 64];
  __shared__ __align__(16) unsigned short Bs[128 * 64];

  const int m0 = blockIdx.x * 128, n0 = blockIdx.y * 128;
  f32x4 zero4 = {0.f, 0.f, 0.f, 0.f};
  f32x4 acc[4][4];
#pragma unroll
  for (int i = 0; i < 4; ++i)
#pragma unroll
    for (int j = 0; j < 4; ++j) acc[i][j] = zero4;

  gemm_core_128(AO, WO, DMODEL, m0, n0, As, Bs, acc);

  const int t = threadIdx.x, ln = t & 63, w = t >> 6;
  const int wr = w >> 1, wc = w & 1, g = ln >> 4, li = ln & 15;
#pragma unroll
  for (int mi = 0; mi < 4; ++mi)
#pragma unroll
    for (int ni = 0; ni < 4; ++ni)
#pragma unroll
      for (int r = 0; r < 4; ++r) {
        int row = m0 + wr*64 + mi*16 + g*4 + r;
        int col = n0 + wc*64 + ni*16 + li;
        Cout[(size_t)row * DMODEL + col] = acc[mi][ni][r];
      }
}

// ---------------------------------------------------------------------------
// RMSNorm + RoPE in place on Q,K slabs (bf16). One wave per row.
// ---------------------------------------------------------------------------
__global__ __launch_bounds__(256) void k_rope(
    unsigned short* __restrict__ Q, unsigned short* __restrict__ K,
    const float* __restrict__ qw, const float* __restrict__ kw)
{
  const int t = threadIdx.x, ln = t & 63, w = t >> 6;
  const int rid = blockIdx.x * 4 + w;          // 0..49151
  const int tt  = rid & (TSEQ - 1);
  const size_t base = (size_t)rid * HDIM;

  const float ang = (float)tt * exp2f(-0.31143075464f * (float)ln);
  float s, c;
  sincosf(ang, &s, &c);

#pragma unroll
  for (int which = 0; which < 2; ++which) {
    unsigned short* P = which ? K : Q;
    const float* Wn = which ? kw : qw;
    float x1 = bf2f(P[base + ln]);
    float x2 = bf2f(P[base + 64 + ln]);
    float ss = x1 * x1 + x2 * x2;
#pragma unroll
    for (int off = 1; off < 64; off <<= 1) ss += __shfl_xor(ss, off, 64);
    float rr = rsqrtf(ss * (1.0f / 128.0f) + 1.1920928955078125e-07f);
    float y1 = x1 * rr * Wn[ln];
    float y2 = x2 * rr * Wn[64 + ln];
    P[base + ln]      = f2bf(y1 * c - y2 * s);
    P[base + 64 + ln] = f2bf(y2 * c + y1 * s);
  }
}

// ---------------------------------------------------------------------------
// V transpose: V[slab][t][d] -> VT[slab][d][t]. Tile 64t x 64d, LDS stride 65
// (odd stride => scalar read/write both land ~2 lanes/bank, global R/W coalesced)
// ---------------------------------------------------------------------------
__global__ __launch_bounds__(256) void k_vtrans(
    const unsigned short* __restrict__ V, unsigned short* __restrict__ VT)
{
  __shared__ unsigned short L[64 * 65];
  const int tb = blockIdx.x;          // t-tile 0..31
  const int db = blockIdx.y;          // d-tile 0..1
  const int sl = blockIdx.z;          // slab 0..23
  const size_t slab = (size_t)sl * (TSEQ * HDIM);
  const int t = threadIdx.x;

#pragma unroll
  for (int i = 0; i < 2; ++i) {
    int c = i * 256 + t;              // 512 chunks of 8 elems
    int trow = c >> 3, d0 = (c & 7) * 8;
    bf16x8 vv = *(const bf16x8*)(V + slab + (size_t)(tb*64 + trow) * HDIM + db*64 + d0);
#pragma unroll
    for (int j = 0; j < 8; ++j) L[trow * 65 + d0 + j] = (unsigned short)vv[j];
  }
  __syncthreads();
#pragma unroll
  for (int i = 0; i < 2; ++i) {
    int c = i * 256 + t;
    int drow = c >> 3, t0 = (c & 7) * 8;
    bf16x8 ov;
#pragma unroll
    for (int j = 0; j < 8; ++j) ov[j] = (short)L[(t0 + j) * 65 + drow];
    *(bf16x8*)(VT + slab + (size_t)(db*64 + drow) * TSEQ + tb*64 + t0) = ov;
  }
}

// ---------------------------------------------------------------------------
// Flash attention phase. MODE: 0 causal, 1 anti-causal, 2 bidirectional.
// Block = 4 waves, QBLK=64 (16 q-rows per wave), KVBLK=64.
// ---------------------------------------------------------------------------
#define ATT_SCALE 0.08838834764831845f

template<int MODE>
__device__ __forceinline__ void flash_phase(
    int qt, int bh,
    const unsigned short* __restrict__ Q, const unsigned short* __restrict__ K,
    const unsigned short* __restrict__ VT, unsigned short* __restrict__ AO,
    unsigned short* Ks, unsigned short* Vt, unsigned short* Ps)
{
  const int br = MODE;
  const int b = bh >> 2, h = bh & 3;
  const int t = threadIdx.x, ln = t & 63, w = t >> 6;
  const int g = ln >> 4, li = ln & 15;
  const size_t slab = (size_t)(br * 8 + bh) * (TSEQ * HDIM);
  const int q0 = qt * 64;

  bf16x8 qf[4];
  {
    const unsigned short* qp = Q + slab + (size_t)(q0 + w*16 + li) * HDIM + g*8;
#pragma unroll
    for (int s = 0; s < 4; ++s) qf[s] = *(const bf16x8*)(qp + s * 32);
  }

  f32x4 zero4 = {0.f, 0.f, 0.f, 0.f};
  f32x4 acc_o[8];
#pragma unroll
  for (int fd = 0; fd < 8; ++fd) acc_o[fd] = zero4;
  float m_run[4], l_run[4];
#pragma unroll
  for (int r = 0; r < 4; ++r) { m_run[r] = -1e30f; l_run[r] = 0.f; }

  const int kt0 = (MODE == 1) ? qt : 0;
  const int kt1 = (MODE == 0) ? qt : 31;
  unsigned short* Pw = Ps + w * (16 * 72);

  for (int kt = kt0; kt <= kt1; ++kt) {
    const int k0 = kt * 64;
    __syncthreads();   // prior tile's (or phase's) LDS reads done

    // stage K tile [64 kv][128 d] -> Ks, row stride 136
#pragma unroll
    for (int i = 0; i < 4; ++i) {
      int c2 = i * 256 + t;                 // 1024 chunks of 8 elems
      int kr = c2 >> 4, c16 = c2 & 15;
      *(bf16x8*)(Ks + kr * 136 + c16 * 8) =
          *(const bf16x8*)(K + slab + (size_t)(k0 + kr) * HDIM + c16 * 8);
    }
    // stage V^T tile [128 d][64 kv] -> Vt, row stride 72 (coalesced b128 both sides)
#pragma unroll
    for (int i = 0; i < 4; ++i) {
      int c2 = i * 256 + t;
      int dr = c2 >> 3, t0c = (c2 & 7) * 8;
      *(bf16x8*)(Vt + dr * 72 + t0c) =
          *(const bf16x8*)(VT + slab + (size_t)dr * TSEQ + k0 + t0c);
    }
    __syncthreads();

    // S = Q K^T : per wave 16q x 64k
    f32x4 sf[4];
#pragma unroll
    for (int fc = 0; fc < 4; ++fc) sf[fc] = zero4;
#pragma unroll
    for (int s = 0; s < 4; ++s) {
      bf16x8 kf[4];
#pragma unroll
      for (int fc = 0; fc < 4; ++fc)
        kf[fc] = *(const bf16x8*)(Ks + (fc*16 + li) * 136 + s*32 + g*8);
#pragma unroll
      for (int fc = 0; fc < 4; ++fc)
        sf[fc] = __builtin_amdgcn_mfma_f32_16x16x32_bf16(qf[s], kf[fc], sf[fc], 0, 0, 0);
    }

    const bool diag = (MODE != 2) && (kt == qt);
    float pp[4][4];
#pragma unroll
    for (int fc = 0; fc < 4; ++fc)
#pragma unroll
      for (int r = 0; r < 4; ++r) {
        float sv = sf[fc][r] * ATT_SCALE;
        if (diag) {
          int kg = k0 + fc*16 + li;
          int qg = q0 + w*16 + g*4 + r;
          bool ok = (MODE == 0) ? (kg <= qg) : (kg >= qg);
          sv = ok ? sv : -1e30f;
        }
        pp[fc][r] = sv;
      }

    // online softmax per row
#pragma unroll
    for (int r = 0; r < 4; ++r) {
      float rm = fmaxf(fmaxf(pp[0][r], pp[1][r]), fmaxf(pp[2][r], pp[3][r]));
      rm = fmaxf(rm, __shfl_xor(rm, 1, 64));
      rm = fmaxf(rm, __shfl_xor(rm, 2, 64));
      rm = fmaxf(rm, __shfl_xor(rm, 4, 64));
      rm = fmaxf(rm, __shfl_xor(rm, 8, 64));
      float mn = fmaxf(m_run[r], rm);
      float alpha = __expf(m_run[r] - mn);
      m_run[r] = mn;
      float rs = 0.f;
#pragma unroll
      for (int fc = 0; fc < 4; ++fc) {
        float p = __expf(pp[fc][r] - mn);
        pp[fc][r] = p;
        rs += p;
      }
      rs += __shfl_xor(rs, 1, 64);
      rs += __shfl_xor(rs, 2, 64);
      rs += __shfl_xor(rs, 4, 64);
      rs += __shfl_xor(rs, 8, 64);
      l_run[r] = l_run[r] * alpha + rs;
#pragma unroll
      for (int fd = 0; fd < 8; ++fd) acc_o[fd][r] *= alpha;
    }

    // P -> LDS (wave-private), then PV
#pragma unroll
    for (int fc = 0; fc < 4; ++fc)
#pragma unroll
      for (int r = 0; r < 4; ++r)
        Pw[(g*4 + r) * 72 + fc*16 + li] = f2bf(pp[fc][r]);

    asm volatile("s_waitcnt lgkmcnt(0)" ::: "memory");
    __builtin_amdgcn_sched_barrier(0);

#pragma unroll
    for (int ks = 0; ks < 2; ++ks) {
      bf16x8 pa = *(const bf16x8*)(Pw + li * 72 + ks*32 + g*8);
#pragma unroll
      for (int fd = 0; fd < 8; ++fd) {
        bf16x8 vb = *(const bf16x8*)(Vt + (fd*16 + li) * 72 + ks*32 + g*8);
        acc_o[fd] = __builtin_amdgcn_mfma_f32_16x16x32_bf16(pa, vb, acc_o[fd], 0, 0, 0);
      }
    }
  }

  // epilogue: AO[b][t][br*512 + h*128 + d]
#pragma unroll
  for (int r = 0; r < 4; ++r) {
    float inv = 1.0f / l_run[r];
    int tt = q0 + w*16 + g*4 + r;
    size_t rowbase = ((size_t)b * TSEQ + tt) * DMODEL + br * 512 + h * HDIM;
#pragma unroll
    for (int fd = 0; fd < 8; ++fd)
      AO[rowbase + fd*16 + li] = f2bf(acc_o[fd][r] * inv);
  }
}

// grid (32, 8, 2): z=0 -> causal(qt) + anti-causal(qt) fused (33 tiles),
//                  z=1 -> bidirectional (32 tiles). Balanced.
__global__ __launch_bounds__(256) void k_attn(
    const unsigned short* __restrict__ Q, const unsigned short* __restrict__ K,
    const unsigned short* __restrict__ VT, unsigned short* __restrict__ AO)
{
  __shared__ __align__(16) unsigned short Ks[64 * 136];
  __shared__ __align__(16) unsigned short Vt[128 * 72];
  __shared__ __align__(16) unsigned short Ps[4 * 16 * 72];

  const int qt = blockIdx.x;
  const int bh = blockIdx.y;
  if (blockIdx.z == 0) {
    flash_phase<0>(qt, bh, Q, K, VT, AO, Ks, Vt, Ps);
    flash_phase<1>(qt, bh, Q, K, VT, AO, Ks, Vt, Ps);
  } else {
    flash_phase<2>(qt, bh, Q, K, VT, AO, Ks, Vt, Ps);
  }
}

// ---------------------------------------------------------------------------
extern "C" void kernel_launch(void* const* d_in, const int* in_sizes, int n_in,
                              void* d_out, int out_size, void* d_ws, size_t ws_size,
                              hipStream_t stream)
{
  (void)in_sizes; (void)n_in; (void)out_size; (void)ws_size;
  const float* Xf  = (const float*)d_in[0];
  const float* WOf = (const float*)d_in[10];
  const float* qw  = (const float*)d_in[11];
  const float* kw  = (const float*)d_in[12];

  const size_t S = (size_t)NBR * 2 * NHB * TSEQ * HDIM;       // 6,291,456 elems
  unsigned short* Qs   = (unsigned short*)d_ws;                // S
  unsigned short* Ks   = Qs + S;                               // S
  unsigned short* Vs   = Ks + S;                               // S
  unsigned short* AO   = Vs + S;                               // S
  unsigned short* Xbf  = AO + S;                               // S (= MROWS*DMODEL)
  unsigned short* Wbf  = Xbf + (size_t)MROWS * DMODEL;         // 9*512*1536
  unsigned short* WObf = Wbf + (size_t)9 * 512 * DMODEL;       // 1536*1536
  unsigned short* VTs  = Xbf;   // reuse: Xbf dead after k_gemm_qkv
  float* Cout = (float*)d_out;

  dim3 blk(256);

  k_cvt<<<dim3((MROWS * DMODEL) / 1024), blk, 0, stream>>>(Xf, Xbf, (MROWS * DMODEL) / 4);
  W9 w9;
  for (int i = 0; i < 9; ++i) w9.w[i] = (const float*)d_in[1 + i];
  k_cvt9<<<dim3((512 * DMODEL) / 1024, 9), blk, 0, stream>>>(w9, Wbf, (512 * DMODEL) / 4);
  k_cvt<<<dim3((DMODEL * DMODEL) / 1024), blk, 0, stream>>>(WOf, WObf, (DMODEL * DMODEL) / 4);

  k_gemm_qkv<<<dim3(32, 4, 9), blk, 0, stream>>>(Xbf, Wbf, Qs, Ks, Vs);
  k_rope<<<dim3(12288), blk, 0, stream>>>(Qs, Ks, qw, kw);
  k_vtrans<<<dim3(32, 2, 24), blk, 0, stream>>>(Vs, VTs);
  k_attn<<<dim3(32, 8, 2), blk, 0, stream>>>(Qs, Ks, VTs, AO);
  k_gemm_out<<<dim3(32, 12), blk, 0, stream>>>(AO, WObf, Cout);
}

// Round 4
// 227.604 us; speedup vs baseline: 1.9535x; 1.1893x over previous
//
#include <hip/hip_runtime.h>
#include <stdint.h>
#include <stddef.h>

typedef __attribute__((ext_vector_type(8))) short bf16x8;
typedef __attribute__((ext_vector_type(4))) float f32x4;

#define DMODEL 1536
#define TSEQ   2048
#define HDIM   128
#define NBR    3
#define NHB    4      // heads per branch
#define MROWS  4096   // B*T

__device__ __forceinline__ float bf2f(unsigned short u) {
  union { unsigned int i; float f; } v; v.i = ((unsigned int)u) << 16; return v.f;
}
__device__ __forceinline__ unsigned short f2bf(float f) {
  union { float f; unsigned int i; } v; v.f = f;
  unsigned int r = v.i + 0x7fffu + ((v.i >> 16) & 1u);
  return (unsigned short)(r >> 16);
}
__device__ __forceinline__ void gload_lds16(const void* g, void* l) {
  __builtin_amdgcn_global_load_lds((__attribute__((address_space(1))) void*)g,
                                   (__attribute__((address_space(3))) void*)l,
                                   16, 0, 0);
}

// ---------------------------------------------------------------------------
// f32 -> bf16 conversion kernels (pre-pass)
// ---------------------------------------------------------------------------
__global__ __launch_bounds__(256) void k_cvt(const float* __restrict__ src,
                                             unsigned short* __restrict__ dst,
                                             int n4) {
  int i = blockIdx.x * 256 + threadIdx.x;
  if (i >= n4) return;
  float4 v = ((const float4*)src)[i];
  ushort4 o;
  o.x = f2bf(v.x); o.y = f2bf(v.y); o.z = f2bf(v.z); o.w = f2bf(v.w);
  ((ushort4*)dst)[i] = o;
}

struct W9 { const float* w[9]; };

__global__ __launch_bounds__(256) void k_cvt9(W9 ws, unsigned short* __restrict__ dst,
                                              int n4) {
  int seg = blockIdx.y;
  const float* __restrict__ src = ws.w[seg];
  unsigned short* __restrict__ d = dst + (size_t)seg * (size_t)n4 * 4;
  int i = blockIdx.x * 256 + threadIdx.x;
  if (i >= n4) return;
  float4 v = ((const float4*)src)[i];
  ushort4 o;
  o.x = f2bf(v.x); o.y = f2bf(v.y); o.z = f2bf(v.z); o.w = f2bf(v.w);
  ((ushort4*)d)[i] = o;
}

// ---------------------------------------------------------------------------
// Pipelined GEMM: C = A[4096,1536] * B[N,1536]^T, bf16, tile 128x192x64.
// 512 thr = 8 waves (2M x 4N), per-wave 64x48 (4x3 frags of 16x16x32).
// T2 XOR-swizzle LDS + counted vmcnt(5) 2-deep pipeline + raw barriers + setprio.
// EPI 0: scatter bf16 into Q/K/V slabs (N=4608=9 mats). EPI 1: f32 out (N=1536).
// ---------------------------------------------------------------------------
#define GBM 128
#define GBN 192
#define GBK 64
#define GK  1536
#define GNT (GK / GBK)   // 24 K-tiles

template<int EPI>
__global__ __launch_bounds__(512, 4) void k_gemm8(
    const unsigned short* __restrict__ A, const unsigned short* __restrict__ Bw,
    unsigned short* __restrict__ Qs, unsigned short* __restrict__ Ksl,
    unsigned short* __restrict__ Vs, float* __restrict__ Cout)
{
  __shared__ __align__(16) unsigned short As[2 * GBM * GBK];   // 32 KiB
  __shared__ __align__(16) unsigned short Bs[2 * GBN * GBK];   // 48 KiB

  const int t = threadIdx.x, ln = t & 63, w = t >> 6;
  const int wm = w >> 2, wn = w & 3, g = ln >> 4, li = ln & 15;

  // XCD-aware bijective swizzle (grid count divisible by 8; gridDim.x == 32)
  const int nwg = gridDim.x * gridDim.y;
  const int lid = blockIdx.y * gridDim.x + blockIdx.x;
  const int s = (lid & 7) * (nwg >> 3) + (lid >> 3);
  const int m0 = (s & 31) * GBM;
  const int n0 = (s >> 5) * GBN;

  f32x4 zero4 = {0.f, 0.f, 0.f, 0.f};
  f32x4 acc[4][3];
#pragma unroll
  for (int i = 0; i < 4; ++i)
#pragma unroll
    for (int j = 0; j < 3; ++j) acc[i][j] = zero4;

  // stage K-tile kt into buffer p: LDS linear, global source pre-swizzled
  // (c16 ^= row&7) so swizzled ds_read finds its data (involution, rule #21).
  auto STAGE = [&](int p, int kt) {
    const unsigned short* Ag = A + (size_t)m0 * GK + kt * GBK;
    unsigned short* Al = As + p * (GBM * GBK);
#pragma unroll
    for (int i = 0; i < 2; ++i) {
      int ch = i * 512 + t; int r = ch >> 3, c = ch & 7;
      gload_lds16(Ag + (size_t)r * GK + ((c ^ (r & 7)) * 8), Al + ch * 8);
    }
    const unsigned short* Bg = Bw + (size_t)n0 * GK + kt * GBK;
    unsigned short* Bl = Bs + p * (GBN * GBK);
#pragma unroll
    for (int i = 0; i < 3; ++i) {
      int ch = i * 512 + t; int r = ch >> 3, c = ch & 7;
      gload_lds16(Bg + (size_t)r * GK + ((c ^ (r & 7)) * 8), Bl + ch * 8);
    }
  };

  STAGE(0, 0);
  STAGE(1, 1);

  for (int kt = 0; kt < GNT; ++kt) {
    const int cur = kt & 1;
    // counted wait: 5 loads/wave/K-tile; keep next tile's 5 in flight
    if (kt < GNT - 1) { asm volatile("s_waitcnt vmcnt(5)" ::: "memory"); }
    else              { asm volatile("s_waitcnt vmcnt(0)" ::: "memory"); }
    __builtin_amdgcn_sched_barrier(0);
    __builtin_amdgcn_s_barrier();          // buf[cur] valid for everyone
    __builtin_amdgcn_sched_barrier(0);
    asm volatile("" ::: "memory");

    const unsigned short* Al = As + cur * (GBM * GBK);
    const unsigned short* Bl = Bs + cur * (GBN * GBK);
#pragma unroll
    for (int kh = 0; kh < 2; ++kh) {
      bf16x8 af[4], bfn[3];
#pragma unroll
      for (int mf = 0; mf < 4; ++mf) {
        int r = wm * 64 + mf * 16 + li;
        af[mf] = *(const bf16x8*)(Al + r * 64 + (((kh * 4 + g) ^ (li & 7)) * 8));
      }
#pragma unroll
      for (int nf = 0; nf < 3; ++nf) {
        int r = wn * 48 + nf * 16 + li;
        bfn[nf] = *(const bf16x8*)(Bl + r * 64 + (((kh * 4 + g) ^ (li & 7)) * 8));
      }
      __builtin_amdgcn_s_setprio(1);
#pragma unroll
      for (int mf = 0; mf < 4; ++mf)
#pragma unroll
        for (int nf = 0; nf < 3; ++nf)
          acc[mf][nf] = __builtin_amdgcn_mfma_f32_16x16x32_bf16(
              af[mf], bfn[nf], acc[mf][nf], 0, 0, 0);
      __builtin_amdgcn_s_setprio(0);
    }
    asm volatile("" ::: "memory");
    __builtin_amdgcn_sched_barrier(0);
    __builtin_amdgcn_s_barrier();          // all reads of buf[cur] done
    __builtin_amdgcn_sched_barrier(0);
    if (kt + 2 < GNT) STAGE(cur, kt + 2);
  }

  // epilogue
#pragma unroll
  for (int mf = 0; mf < 4; ++mf)
#pragma unroll
    for (int nf = 0; nf < 3; ++nf)
#pragma unroll
      for (int rr = 0; rr < 4; ++rr) {
        int row = m0 + wm * 64 + mf * 16 + g * 4 + rr;
        int col = n0 + wn * 48 + nf * 16 + li;
        if (EPI == 0) {
          int mat = col >> 9, within = col & 511;
          int br = mat / 3, qkv = mat % 3;
          int b = row >> 11, tt = row & 2047;
          int h = within >> 7, d = within & 127;
          unsigned short* dst = (qkv == 0) ? Qs : (qkv == 1) ? Ksl : Vs;
          size_t off = ((size_t)((br * 2 + b) * 4 + h) * TSEQ + tt) * HDIM + d;
          dst[off] = f2bf(acc[mf][nf][rr]);
        } else {
          Cout[(size_t)row * DMODEL + col] = acc[mf][nf][rr];
        }
      }
}

// ---------------------------------------------------------------------------
// RMSNorm + RoPE in place on Q,K slabs (bf16). One wave per row.
// ---------------------------------------------------------------------------
__global__ __launch_bounds__(256) void k_rope(
    unsigned short* __restrict__ Q, unsigned short* __restrict__ K,
    const float* __restrict__ qw, const float* __restrict__ kw)
{
  const int t = threadIdx.x, ln = t & 63, w = t >> 6;
  const int rid = blockIdx.x * 4 + w;          // 0..49151
  const int tt  = rid & (TSEQ - 1);
  const size_t base = (size_t)rid * HDIM;

  const float ang = (float)tt * exp2f(-0.31143075464f * (float)ln);
  float s, c;
  sincosf(ang, &s, &c);

#pragma unroll
  for (int which = 0; which < 2; ++which) {
    unsigned short* P = which ? K : Q;
    const float* Wn = which ? kw : qw;
    float x1 = bf2f(P[base + ln]);
    float x2 = bf2f(P[base + 64 + ln]);
    float ss = x1 * x1 + x2 * x2;
#pragma unroll
    for (int off = 1; off < 64; off <<= 1) ss += __shfl_xor(ss, off, 64);
    float rr = rsqrtf(ss * (1.0f / 128.0f) + 1.1920928955078125e-07f);
    float y1 = x1 * rr * Wn[ln];
    float y2 = x2 * rr * Wn[64 + ln];
    P[base + ln]      = f2bf(y1 * c - y2 * s);
    P[base + 64 + ln] = f2bf(y2 * c + y1 * s);
  }
}

// ---------------------------------------------------------------------------
// V transpose: V[slab][t][d] -> VT[slab][d][t]. Tile 64t x 64d, LDS stride 65
// ---------------------------------------------------------------------------
__global__ __launch_bounds__(256) void k_vtrans(
    const unsigned short* __restrict__ V, unsigned short* __restrict__ VT)
{
  __shared__ unsigned short L[64 * 65];
  const int tb = blockIdx.x;          // t-tile 0..31
  const int db = blockIdx.y;          // d-tile 0..1
  const int sl = blockIdx.z;          // slab 0..23
  const size_t slab = (size_t)sl * (TSEQ * HDIM);
  const int t = threadIdx.x;

#pragma unroll
  for (int i = 0; i < 2; ++i) {
    int c = i * 256 + t;              // 512 chunks of 8 elems
    int trow = c >> 3, d0 = (c & 7) * 8;
    bf16x8 vv = *(const bf16x8*)(V + slab + (size_t)(tb*64 + trow) * HDIM + db*64 + d0);
#pragma unroll
    for (int j = 0; j < 8; ++j) L[trow * 65 + d0 + j] = (unsigned short)vv[j];
  }
  __syncthreads();
#pragma unroll
  for (int i = 0; i < 2; ++i) {
    int c = i * 256 + t;
    int drow = c >> 3, t0 = (c & 7) * 8;
    bf16x8 ov;
#pragma unroll
    for (int j = 0; j < 8; ++j) ov[j] = (short)L[(t0 + j) * 65 + drow];
    *(bf16x8*)(VT + slab + (size_t)(db*64 + drow) * TSEQ + tb*64 + t0) = ov;
  }
}

// ---------------------------------------------------------------------------
// Flash attention phase. MODE: 0 causal, 1 anti-causal, 2 bidirectional.
// ---------------------------------------------------------------------------
#define ATT_SCALE 0.08838834764831845f

template<int MODE>
__device__ __forceinline__ void flash_phase(
    int qt, int bh,
    const unsigned short* __restrict__ Q, const unsigned short* __restrict__ K,
    const unsigned short* __restrict__ VT, unsigned short* __restrict__ AO,
    unsigned short* Ks, unsigned short* Vt, unsigned short* Ps)
{
  const int br = MODE;
  const int b = bh >> 2, h = bh & 3;
  const int t = threadIdx.x, ln = t & 63, w = t >> 6;
  const int g = ln >> 4, li = ln & 15;
  const size_t slab = (size_t)(br * 8 + bh) * (TSEQ * HDIM);
  const int q0 = qt * 64;

  bf16x8 qf[4];
  {
    const unsigned short* qp = Q + slab + (size_t)(q0 + w*16 + li) * HDIM + g*8;
#pragma unroll
    for (int s = 0; s < 4; ++s) qf[s] = *(const bf16x8*)(qp + s * 32);
  }

  f32x4 zero4 = {0.f, 0.f, 0.f, 0.f};
  f32x4 acc_o[8];
#pragma unroll
  for (int fd = 0; fd < 8; ++fd) acc_o[fd] = zero4;
  float m_run[4], l_run[4];
#pragma unroll
  for (int r = 0; r < 4; ++r) { m_run[r] = -1e30f; l_run[r] = 0.f; }

  const int kt0 = (MODE == 1) ? qt : 0;
  const int kt1 = (MODE == 0) ? qt : 31;
  unsigned short* Pw = Ps + w * (16 * 72);

  for (int kt = kt0; kt <= kt1; ++kt) {
    const int k0 = kt * 64;
    __syncthreads();   // prior tile's (or phase's) LDS reads done

    // stage K tile [64 kv][128 d] -> Ks, row stride 136
#pragma unroll
    for (int i = 0; i < 4; ++i) {
      int c2 = i * 256 + t;                 // 1024 chunks of 8 elems
      int kr = c2 >> 4, c16 = c2 & 15;
      *(bf16x8*)(Ks + kr * 136 + c16 * 8) =
          *(const bf16x8*)(K + slab + (size_t)(k0 + kr) * HDIM + c16 * 8);
    }
    // stage V^T tile [128 d][64 kv] -> Vt, row stride 72
#pragma unroll
    for (int i = 0; i < 4; ++i) {
      int c2 = i * 256 + t;
      int dr = c2 >> 3, t0c = (c2 & 7) * 8;
      *(bf16x8*)(Vt + dr * 72 + t0c) =
          *(const bf16x8*)(VT + slab + (size_t)dr * TSEQ + k0 + t0c);
    }
    __syncthreads();

    // S = Q K^T : per wave 16q x 64k
    f32x4 sf[4];
#pragma unroll
    for (int fc = 0; fc < 4; ++fc) sf[fc] = zero4;
#pragma unroll
    for (int s = 0; s < 4; ++s) {
      bf16x8 kf[4];
#pragma unroll
      for (int fc = 0; fc < 4; ++fc)
        kf[fc] = *(const bf16x8*)(Ks + (fc*16 + li) * 136 + s*32 + g*8);
#pragma unroll
      for (int fc = 0; fc < 4; ++fc)
        sf[fc] = __builtin_amdgcn_mfma_f32_16x16x32_bf16(qf[s], kf[fc], sf[fc], 0, 0, 0);
    }

    const bool diag = (MODE != 2) && (kt == qt);
    float pp[4][4];
#pragma unroll
    for (int fc = 0; fc < 4; ++fc)
#pragma unroll
      for (int r = 0; r < 4; ++r) {
        float sv = sf[fc][r] * ATT_SCALE;
        if (diag) {
          int kg = k0 + fc*16 + li;
          int qg = q0 + w*16 + g*4 + r;
          bool ok = (MODE == 0) ? (kg <= qg) : (kg >= qg);
          sv = ok ? sv : -1e30f;
        }
        pp[fc][r] = sv;
      }

    // online softmax per row
#pragma unroll
    for (int r = 0; r < 4; ++r) {
      float rm = fmaxf(fmaxf(pp[0][r], pp[1][r]), fmaxf(pp[2][r], pp[3][r]));
      rm = fmaxf(rm, __shfl_xor(rm, 1, 64));
      rm = fmaxf(rm, __shfl_xor(rm, 2, 64));
      rm = fmaxf(rm, __shfl_xor(rm, 4, 64));
      rm = fmaxf(rm, __shfl_xor(rm, 8, 64));
      float mn = fmaxf(m_run[r], rm);
      float alpha = __expf(m_run[r] - mn);
      m_run[r] = mn;
      float rs = 0.f;
#pragma unroll
      for (int fc = 0; fc < 4; ++fc) {
        float p = __expf(pp[fc][r] - mn);
        pp[fc][r] = p;
        rs += p;
      }
      rs += __shfl_xor(rs, 1, 64);
      rs += __shfl_xor(rs, 2, 64);
      rs += __shfl_xor(rs, 4, 64);
      rs += __shfl_xor(rs, 8, 64);
      l_run[r] = l_run[r] * alpha + rs;
#pragma unroll
      for (int fd = 0; fd < 8; ++fd) acc_o[fd][r] *= alpha;
    }

    // P -> LDS (wave-private), then PV
#pragma unroll
    for (int fc = 0; fc < 4; ++fc)
#pragma unroll
      for (int r = 0; r < 4; ++r)
        Pw[(g*4 + r) * 72 + fc*16 + li] = f2bf(pp[fc][r]);

    asm volatile("s_waitcnt lgkmcnt(0)" ::: "memory");
    __builtin_amdgcn_sched_barrier(0);

#pragma unroll
    for (int ks = 0; ks < 2; ++ks) {
      bf16x8 pa = *(const bf16x8*)(Pw + li * 72 + ks*32 + g*8);
#pragma unroll
      for (int fd = 0; fd < 8; ++fd) {
        bf16x8 vb = *(const bf16x8*)(Vt + (fd*16 + li) * 72 + ks*32 + g*8);
        acc_o[fd] = __builtin_amdgcn_mfma_f32_16x16x32_bf16(pa, vb, acc_o[fd], 0, 0, 0);
      }
    }
  }

  // epilogue: AO[b][t][br*512 + h*128 + d]
#pragma unroll
  for (int r = 0; r < 4; ++r) {
    float inv = 1.0f / l_run[r];
    int tt = q0 + w*16 + g*4 + r;
    size_t rowbase = ((size_t)b * TSEQ + tt) * DMODEL + br * 512 + h * HDIM;
#pragma unroll
    for (int fd = 0; fd < 8; ++fd)
      AO[rowbase + fd*16 + li] = f2bf(acc_o[fd][r] * inv);
  }
}

// grid (32, 8, 2): z=0 -> causal+anti-causal fused, z=1 -> bidirectional.
__global__ __launch_bounds__(256) void k_attn(
    const unsigned short* __restrict__ Q, const unsigned short* __restrict__ K,
    const unsigned short* __restrict__ VT, unsigned short* __restrict__ AO)
{
  __shared__ __align__(16) unsigned short Ks[64 * 136];
  __shared__ __align__(16) unsigned short Vt[128 * 72];
  __shared__ __align__(16) unsigned short Ps[4 * 16 * 72];

  const int qt = blockIdx.x;
  const int bh = blockIdx.y;
  if (blockIdx.z == 0) {
    flash_phase<0>(qt, bh, Q, K, VT, AO, Ks, Vt, Ps);
    flash_phase<1>(qt, bh, Q, K, VT, AO, Ks, Vt, Ps);
  } else {
    flash_phase<2>(qt, bh, Q, K, VT, AO, Ks, Vt, Ps);
  }
}

// ---------------------------------------------------------------------------
extern "C" void kernel_launch(void* const* d_in, const int* in_sizes, int n_in,
                              void* d_out, int out_size, void* d_ws, size_t ws_size,
                              hipStream_t stream)
{
  (void)in_sizes; (void)n_in; (void)out_size; (void)ws_size;
  const float* Xf  = (const float*)d_in[0];
  const float* WOf = (const float*)d_in[10];
  const float* qw  = (const float*)d_in[11];
  const float* kw  = (const float*)d_in[12];

  const size_t S = (size_t)NBR * 2 * NHB * TSEQ * HDIM;       // 6,291,456 elems
  unsigned short* Qs   = (unsigned short*)d_ws;                // S
  unsigned short* Ks   = Qs + S;                               // S
  unsigned short* Vs   = Ks + S;                               // S
  unsigned short* AO   = Vs + S;                               // S
  unsigned short* Xbf  = AO + S;                               // S (= MROWS*DMODEL)
  unsigned short* Wbf  = Xbf + (size_t)MROWS * DMODEL;         // 9*512*1536
  unsigned short* WObf = Wbf + (size_t)9 * 512 * DMODEL;       // 1536*1536
  unsigned short* VTs  = Xbf;   // reuse: Xbf dead after k_gemm8<0>
  float* Cout = (float*)d_out;

  dim3 blk(256);

  k_cvt<<<dim3((MROWS * DMODEL) / 1024), blk, 0, stream>>>(Xf, Xbf, (MROWS * DMODEL) / 4);
  W9 w9;
  for (int i = 0; i < 9; ++i) w9.w[i] = (const float*)d_in[1 + i];
  k_cvt9<<<dim3((512 * DMODEL) / 1024, 9), blk, 0, stream>>>(w9, Wbf, (512 * DMODEL) / 4);
  k_cvt<<<dim3((DMODEL * DMODEL) / 1024), blk, 0, stream>>>(WOf, WObf, (DMODEL * DMODEL) / 4);

  // fused QKV projection: [4096, 4608] = X @ Wall^T, grid 768 = 3*256
  k_gemm8<0><<<dim3(32, 24), dim3(512), 0, stream>>>(Xbf, Wbf, Qs, Ks, Vs, nullptr);
  k_rope<<<dim3(12288), blk, 0, stream>>>(Qs, Ks, qw, kw);
  k_vtrans<<<dim3(32, 2, 24), blk, 0, stream>>>(Vs, VTs);
  k_attn<<<dim3(32, 8, 2), blk, 0, stream>>>(Qs, Ks, VTs, AO);
  // output projection: [4096, 1536] = AO @ wo^T, grid 256
  k_gemm8<1><<<dim3(32, 8), dim3(512), 0, stream>>>(AO, WObf, nullptr, nullptr, nullptr, Cout);
}